// Round 2
// baseline (307.056 us; speedup 1.0000x reference)
//
#include <hip/hip_runtime.h>

// Problem constants
#define B_ 4
#define C_ 64
#define F_ 64
#define T_ 128
#define IC_ 32
#define N_ 8192
#define M_ 2048

// Scratch layout (float units; all fp32 intermediates)
#define OFF_U      0           // B*N
#define OFF_PSI2   32768       // B*M*IC, layout [b][m][c]
#define OFF_V      294912      // B*M
#define OFF_VS     303104      // B*M sorted v (descending)
#define OFF_Q01    311296      // B*2049*64 float2 (z-prefix, vz-prefix), layout [b][k][o]
#define WS_FLOATS  1360384     // 5.44 MB static device scratch

__device__ __align__(16) float g_ws[WS_FLOATS];
__device__ int g_perm[B_ * M_];
__device__ unsigned g_bar;     // monotonic ticket counter (never reset; survives replays)

#define GRID_ 256

// Software grid barrier: monotonic tickets, agent-scope atomics, no cooperative
// API (graph-capture-safe). Requires all GRID_ blocks co-resident: guaranteed by
// __launch_bounds__(256,2) -> 2 blocks/CU capacity = 512 slots >= 256 blocks.
__device__ __forceinline__ void grid_barrier(int tid)
{
    __threadfence();           // release: wb L2 so other XCDs see our writes
    __syncthreads();
    if (tid == 0) {
        const unsigned t = __hip_atomic_fetch_add(&g_bar, 1u, __ATOMIC_ACQ_REL,
                                                  __HIP_MEMORY_SCOPE_AGENT) + 1u;
        const unsigned goal = (t + (GRID_ - 1u)) & ~(GRID_ - 1u);
        while (__hip_atomic_load(&g_bar, __ATOMIC_ACQUIRE,
                                 __HIP_MEMORY_SCOPE_AGENT) < goal)
            __builtin_amdgcn_s_sleep(2);
    }
    __syncthreads();
    __threadfence();           // acquire: inv L1/L2 before reading remote data
}

// ---------------------------------------------------------------------------
// Fused kernel: 256 blocks x 256 thr, launch_bounds(256,2) -> deadlock-safe
// co-residency margin. Each block: 2 phase-1 tiles, 2 phase-2 chunks,
// 1 phase-3 (b,o), 2 phase-4 tiles. 3 software grid barriers replace the
// 3 kernel boundaries. Shared memory: one 33 KB buffer aliased per phase.
// ---------------------------------------------------------------------------
__global__ __launch_bounds__(256, 2) void fused(
    const float* __restrict__ x,
    const float* __restrict__ psi_w, const float* __restrict__ psi_b,
    const float* __restrict__ theta_w, const float* __restrict__ theta_b,
    const float* __restrict__ phi_w, const float* __restrict__ phi_b,
    const float* __restrict__ h0_w, const float* __restrict__ h1_w,
    const float* __restrict__ h2_w,
    const float* __restrict__ W_w, const float* __restrict__ W_b,
    const float* __restrict__ bn_g, const float* __restrict__ bn_b,
    const float* __restrict__ bn_m, const float* __restrict__ bn_v,
    float* __restrict__ out)
{
    float* __restrict__ ws = g_ws;
    __shared__ __align__(16) char smem[33024];   // 8256 floats (phase-1 peak)

    const int tid = threadIdx.x;
    const int bid = blockIdx.x;

    // ======================= Phase 1: convs + pool (2 tiles) ==================
    {
        float* xs   = (float*)smem;      // [c][r2(2)][col(32)]        4096
        float* pw   = xs + 4096;         // [(c4*32 + o)*4 + j]        2048
        float* fw   = pw + 2048;         //                            2048
        float* wt_l = fw + 2048;         //                              64

        // stage weights once (tile-independent)
        for (int idx = tid; idx < 2048; idx += 256) {
            const int c4 = idx >> 7, o = (idx >> 2) & 31, j = idx & 3;
            pw[idx] = psi_w[o * 64 + 4 * c4 + j];
            fw[idx] = phi_w[o * 64 + 4 * c4 + j];
        }
        if (tid < 64) {
            float acc = 0.f;
            for (int o2 = 0; o2 < 32; ++o2)
                acc += h0_w[o2] * theta_w[o2 * 64 + tid];
            wt_l[tid] = acc;
        }

        const float h20 = h2_w[0], h21 = h2_w[1];

        for (int half = 0; half < 2; ++half) {
            const int u = 2 * bid + half;          // tile unit [0,512)
            const int b = u >> 7;
            const int rem = u & 127;
            const int fh = rem >> 2;               // [0,32)
            const int q = rem & 3;                 // col-quarter [0,4)
            const int c0 = q * 32;

            __syncthreads();   // weights staged / prev tile's xs readers done

            // stage x tile (float4): 64 ch x rows {2fh,2fh+1} x cols [c0,c0+32)
            for (int idx = tid; idx < 1024; idx += 256) {
                const int c = idx >> 4, r2 = (idx >> 3) & 1, t4 = idx & 7;
                const float4 v = *(const float4*)&x[(((size_t)b * 64 + c) * 64 + (2 * fh + r2)) * 128 + c0 + 4 * t4];
                *(float4*)&xs[c * 64 + r2 * 32 + 4 * t4] = v;
            }
            __syncthreads();

            // conv + pool: thread=(o in [0,32), g in [0,8)); half-cols 2g, 2g+1
            {
                const int o = tid & 31, g = tid >> 5;
                const float pb = psi_b[o], fb = phi_b[o], h1 = h1_w[o];
                const float4* pw4 = (const float4*)pw;
                const float4* fw4 = (const float4*)fw;
                const float4* xs4 = (const float4*)xs;
                float sp[2][4] = {{0,0,0,0},{0,0,0,0}};
                float sf[2][4] = {{0,0,0,0},{0,0,0,0}};
                for (int c4 = 0; c4 < 16; ++c4) {
                    const float4 pv = pw4[c4 * 32 + o];    // b128, consecutive per lane
                    const float4 fv = fw4[c4 * 32 + o];
                    const float* pvf = (const float*)&pv;
                    const float* fvf = (const float*)&fv;
#pragma unroll
                    for (int j = 0; j < 4; ++j) {
                        const int c = 4 * c4 + j;
                        const float4 r0 = xs4[c * 16 + g];       // broadcast (2 addr/wave)
                        const float4 r1 = xs4[c * 16 + 8 + g];
                        const float wp = pvf[j], wf = fvf[j];
                        sp[0][0] += wp * r0.x; sp[0][1] += wp * r0.y;
                        sp[0][2] += wp * r1.x; sp[0][3] += wp * r1.y;
                        sp[1][0] += wp * r0.z; sp[1][1] += wp * r0.w;
                        sp[1][2] += wp * r1.z; sp[1][3] += wp * r1.w;
                        sf[0][0] += wf * r0.x; sf[0][1] += wf * r0.y;
                        sf[0][2] += wf * r1.x; sf[0][3] += wf * r1.y;
                        sf[1][0] += wf * r0.z; sf[1][1] += wf * r0.w;
                        sf[1][2] += wf * r1.z; sf[1][3] += wf * r1.w;
                    }
                }
#pragma unroll
                for (int h = 0; h < 2; ++h) {
                    const int hc = 2 * g + h;
                    const float psiv = fmaxf(fmaxf(sp[h][0], sp[h][1]), fmaxf(sp[h][2], sp[h][3])) + pb;
                    const float phiv = fmaxf(fmaxf(sf[h][0], sf[h][1]), fmaxf(sf[h][2], sf[h][3])) + fb;
                    const int m = fh * 64 + q * 16 + hc;
                    ws[OFF_PSI2 + ((size_t)b * 2048 + m) * 32 + o] = psiv;
                    float tv = h1 * phiv;
                    for (int mask = 1; mask < 32; mask <<= 1)
                        tv += __shfl_xor(tv, mask, 64);
                    if (o == 0) {
                        const float bpos = h20 * (fh * (1.0f / 31.0f))
                                         + h21 * ((q * 16 + hc) * (1.0f / 63.0f));
                        ws[OFF_V + b * 2048 + m] = tv - bpos;
                    }
                }
            }

            // u[b,n] for the 64 full positions of this tile
            if (tid < 64) {
                const int r2 = tid >> 5, tl = tid & 31;
                float acc = 0.f;
                for (int c = 0; c < 64; ++c)
                    acc += xs[c * 64 + r2 * 32 + tl] * wt_l[c];
                float tb_ = 0.f;
                for (int o2 = 0; o2 < 32; ++o2)
                    tb_ += h0_w[o2] * theta_b[o2];
                const int f = 2 * fh + r2, tt = c0 + tl;
                const int n = f * 128 + tt;
                const float a = h20 * (f * (1.0f / 63.0f)) + h21 * (tt * (1.0f / 127.0f));
                ws[OFF_U + b * 8192 + n] = acc + tb_ + a;
            }
        }
    }

    grid_barrier(tid);

    // ======================= Phase 2: rank sort (2 chunks, same b) ============
    {
        float* vl = (float*)smem;                 // 2048
        int* part = (int*)(vl + 2048);            // 256

        const int u0 = 2 * bid;
        const int b = u0 >> 7;
        const float* v = ws + OFF_V + b * 2048;
        for (int i = tid; i < 2048; i += 256) vl[i] = v[i];
        __syncthreads();

        const float4* v4 = (const float4*)vl;
        for (int half = 0; half < 2; ++half) {
            const int chunk = (u0 & 127) + half;
            const int ml = tid >> 4;        // m within chunk [0,16)
            const int jq = tid & 15;        // j-segment [0,16)
            const int m = chunk * 16 + ml;
            const float vm = vl[m];
            int cnt = 0;
#pragma unroll 4
            for (int i = 0; i < 32; ++i) {
                const int j4 = jq + 16 * i;          // wave reads consecutive float4s
                const float4 vv = v4[j4];
                const int jb = j4 * 4;
                cnt += (vv.x > vm) || (vv.x == vm && (jb    ) < m);
                cnt += (vv.y > vm) || (vv.y == vm && (jb + 1) < m);
                cnt += (vv.z > vm) || (vv.z == vm && (jb + 2) < m);
                cnt += (vv.w > vm) || (vv.w == vm && (jb + 3) < m);
            }
            part[tid] = cnt;
            __syncthreads();
            if (tid < 16) {
                int r = 0;
#pragma unroll
                for (int j = 0; j < 16; ++j) r += part[tid * 16 + j];
                ws[OFF_VS + b * 2048 + r] = vl[chunk * 16 + tid];
                g_perm[b * 2048 + r] = chunk * 16 + tid;
            }
            __syncthreads();   // part[] reuse next half
        }
    }

    grid_barrier(tid);

    // ======================= Phase 3: z + scan -> Q01 =========================
    {
        float* Wrow = (float*)smem;      // 32
        float* wt0  = Wrow + 32;         // 4
        float* wt1  = wt0 + 4;           // 4

        const int b = bid >> 6, o = bid & 63;
        if (tid < 32) Wrow[tid] = W_w[o * 33 + tid];   // W_w is (64,33); col 32 = zero channel
        __syncthreads();

        const int* perm = g_perm + b * 2048;
        const float* vs = ws + OFF_VS + b * 2048;
        const float* psi2 = ws + OFF_PSI2 + (size_t)b * 2048 * 32;

        float zl[8], vlv[8];
        float s0 = 0.f, s1 = 0.f;
        const int base = tid * 8;
#pragma unroll
        for (int qq = 0; qq < 8; ++qq) {
            const int i = base + qq;
            const int mp = perm[i];
            const float4* pr = (const float4*)(psi2 + (size_t)mp * 32);
            float z = 0.f;
#pragma unroll
            for (int w = 0; w < 8; ++w) {
                const float4 p4 = pr[w];
                z += Wrow[4 * w] * p4.x + Wrow[4 * w + 1] * p4.y
                   + Wrow[4 * w + 2] * p4.z + Wrow[4 * w + 3] * p4.w;
            }
            const float vv = vs[i];
            zl[qq] = z; vlv[qq] = vv;
            s0 += z; s1 += vv * z;
        }

        // inclusive wave scan (64 lanes) of per-thread sums
        float w0 = s0, w1 = s1;
        const int lane = tid & 63, wv = tid >> 6;
#pragma unroll
        for (int off = 1; off < 64; off <<= 1) {
            const float t0_ = __shfl_up(w0, off, 64);
            const float t1_ = __shfl_up(w1, off, 64);
            if (lane >= off) { w0 += t0_; w1 += t1_; }
        }
        if (lane == 63) { wt0[wv] = w0; wt1[wv] = w1; }
        __syncthreads();
        float base0 = 0.f, base1 = 0.f;
        for (int w = 0; w < wv; ++w) { base0 += wt0[w]; base1 += wt1[w]; }
        float r0 = w0 + base0 - s0, r1 = w1 + base1 - s1;   // exclusive prefix

        float2* Q01 = (float2*)(ws + OFF_Q01) + (size_t)b * 2049 * 64;
#pragma unroll
        for (int qq = 0; qq < 8; ++qq) {
            r0 += zl[qq]; r1 += vlv[qq] * zl[qq];
            float2 p; p.x = r0; p.y = r1;
            Q01[(size_t)(base + qq + 1) * 64 + o] = p;
        }
        if (tid == 0) { float2 z2; z2.x = 0.f; z2.y = 0.f; Q01[o] = z2; }
    }

    grid_barrier(tid);

    // ======================= Phase 4: gather + epilogue (2 tiles) =============
    {
        float* vsl   = (float*)smem;             // 2048
        float* tileb = vsl + 2048;               // [o][n] pitch 65 -> 4160
        float* uarr  = tileb + 4160;             // 64
        int*   karr  = (int*)(uarr + 64);        // 64

        const int u0 = 2 * bid;
        const int b = u0 >> 7;

        const float* vs = ws + OFF_VS + b * 2048;
        for (int i = tid; i < 2048; i += 256) vsl[i] = vs[i];   // same b both tiles

        const int lane = tid & 63, w = tid >> 6;   // w in [0,4)
        const float inv = bn_g[lane] * __frsqrt_rn(bn_v[lane] + 1e-5f);
        const float sft = W_b[lane] * inv + bn_b[lane] - bn_m[lane] * inv;
        const float2* Q01 = (const float2*)(ws + OFF_Q01) + (size_t)b * 2049 * 64;
        __syncthreads();

        for (int half = 0; half < 2; ++half) {
            const int tile = (u0 & 127) + half;
            const int n0 = tile * 64;

            if (tid < 64) {
                const float u = ws[OFF_U + b * 8192 + n0 + tid];
                const float thr = -u;
                int lo = 0, hi = 2048;
                while (lo < hi) {                  // first idx with vsl[idx] <= -u (descending)
                    const int mid = (lo + hi) >> 1;
                    if (vsl[mid] > thr) lo = mid + 1; else hi = mid;
                }
                karr[tid] = lo;
                uarr[tid] = u;
            }
            __syncthreads();

            for (int nl = w; nl < 64; nl += 4) {
                const int k = karr[nl];
                const float u = uarr[nl];
                const float2 qv = Q01[(size_t)k * 64 + lane];  // 512B coalesced row
                const float raw = (u * qv.x + qv.y) * (1.0f / 2048.0f);
                tileb[lane * 65 + nl] = raw * inv + sft;       // 2-way bank aliasing: free
            }
            __syncthreads();

            for (int idx = tid; idx < 2048; idx += 256) {      // float2 epilogue
                const int o = idx >> 5, j2 = idx & 31;
                const size_t gi = ((size_t)b * 64 + o) * 8192 + n0 + 2 * j2;
                const float2 xv = *(const float2*)&x[gi];
                float2 r;
                r.x = tileb[o * 65 + 2 * j2] + xv.x;
                r.y = tileb[o * 65 + 2 * j2 + 1] + xv.y;
                *(float2*)&out[gi] = r;
            }
            __syncthreads();   // karr/tileb reuse next half
        }
    }
}

// ---------------------------------------------------------------------------
extern "C" void kernel_launch(void* const* d_in, const int* in_sizes, int n_in,
                              void* d_out, int out_size, void* d_ws, size_t ws_size,
                              hipStream_t stream)
{
    (void)in_sizes; (void)n_in; (void)out_size; (void)d_ws; (void)ws_size;
    const float* x       = (const float*)d_in[0];
    const float* psi_w   = (const float*)d_in[1];
    const float* psi_b   = (const float*)d_in[2];
    const float* theta_w = (const float*)d_in[3];
    const float* theta_b = (const float*)d_in[4];
    const float* phi_w   = (const float*)d_in[5];
    const float* phi_b   = (const float*)d_in[6];
    const float* h0_w    = (const float*)d_in[7];
    const float* h1_w    = (const float*)d_in[8];
    const float* h2_w    = (const float*)d_in[9];
    const float* W_w     = (const float*)d_in[10];
    const float* W_b     = (const float*)d_in[11];
    const float* bn_g    = (const float*)d_in[12];
    const float* bn_b    = (const float*)d_in[13];
    const float* bn_m    = (const float*)d_in[14];
    const float* bn_v    = (const float*)d_in[15];
    float* out = (float*)d_out;

    fused<<<dim3(GRID_), dim3(256), 0, stream>>>(
        x, psi_w, psi_b, theta_w, theta_b, phi_w, phi_b,
        h0_w, h1_w, h2_w, W_w, W_b, bn_g, bn_b, bn_m, bn_v, out);
}

// Round 4
// 188.671 us; speedup vs baseline: 1.6275x; 1.6275x over previous
//
#include <hip/hip_runtime.h>

// Problem constants
#define B_ 4
#define C_ 64
#define F_ 64
#define T_ 128
#define IC_ 32
#define N_ 8192
#define M_ 2048

// Scratch layout (float units; all fp32 intermediates)
#define OFF_U      0           // B*N
#define OFF_PSI2   32768       // B*M*IC, layout [b][m][c]
#define OFF_V      294912      // B*M
#define OFF_VS     303104      // B*M sorted v (descending)
#define OFF_Q01    311296      // B*2049*64 float2 (z-prefix, vz-prefix), layout [b][k][o]
#define WS_FLOATS  1360384     // 5.44 MB static device scratch

__device__ __align__(16) float g_ws[WS_FLOATS];
__device__ int g_perm[B_ * M_];
__device__ unsigned g_bar;     // monotonic ticket counter (never reset; survives replays)

#define GRID_ 256

// Software grid barrier: monotonic tickets, graph-capture-safe.
// RACE FIX vs previous round: the ticket increment is an ACQ_REL agent-scope
// RMW. Per the LLVM gfx94x memory model this lowers to
//   s_waitcnt vmcnt(0) lgkmcnt(0); buffer_wbl2 sc1; s_waitcnt vmcnt(0);
//   global_atomic_add
// i.e. the L2 writeback COMPLETES before the ticket becomes visible — a
// remote reader can never observe the ticket while our data is still in this
// XCD's (incoherent) L2. Previous round used fence(release)+RELAXED add,
// which left that publish gap open and raced under replay pressure.
// Spin stays RELAXED (no per-poll buffer_inv storm — that was round 2's
// 232 us); one ACQUIRE fence (buffer_inv: per-CU L1 + XCD L2) on exit.
// Block = 1 CU, so tid0's fences cover the whole block; block stores are
// already drained to L2 by __syncthreads (vmcnt(0) before s_barrier).
// Co-residency: __launch_bounds__(256,2) -> 512 block slots >= 256 blocks.
__device__ __forceinline__ void grid_barrier(int tid)
{
    __syncthreads();           // all block stores drained to this XCD's L2
    if (tid == 0) {
        const unsigned t = __hip_atomic_fetch_add(&g_bar, 1u, __ATOMIC_ACQ_REL,
                                                  __HIP_MEMORY_SCOPE_AGENT) + 1u;
        const unsigned goal = (t + (GRID_ - 1u)) & ~(GRID_ - 1u);
        while (__hip_atomic_load(&g_bar, __ATOMIC_RELAXED,
                                 __HIP_MEMORY_SCOPE_AGENT) < goal)
            __builtin_amdgcn_s_sleep(8);
        __builtin_amdgcn_fence(__ATOMIC_ACQUIRE, "agent");   // inv stale L1/L2
    }
    __syncthreads();
}

// ---------------------------------------------------------------------------
// Fused kernel: 256 blocks x 256 thr, launch_bounds(256,2) -> deadlock-safe
// co-residency margin. Each block: 2 phase-1 tiles, 2 phase-2 chunks,
// 1 phase-3 (b,o), 2 phase-4 tiles. 3 software grid barriers replace the
// 3 kernel boundaries. Shared memory: one 33 KB buffer aliased per phase.
// ---------------------------------------------------------------------------
__global__ __launch_bounds__(256, 2) void fused(
    const float* __restrict__ x,
    const float* __restrict__ psi_w, const float* __restrict__ psi_b,
    const float* __restrict__ theta_w, const float* __restrict__ theta_b,
    const float* __restrict__ phi_w, const float* __restrict__ phi_b,
    const float* __restrict__ h0_w, const float* __restrict__ h1_w,
    const float* __restrict__ h2_w,
    const float* __restrict__ W_w, const float* __restrict__ W_b,
    const float* __restrict__ bn_g, const float* __restrict__ bn_b,
    const float* __restrict__ bn_m, const float* __restrict__ bn_v,
    float* __restrict__ out)
{
    float* __restrict__ ws = g_ws;
    __shared__ __align__(16) char smem[33024];   // 8256 floats (phase-1 peak)

    const int tid = threadIdx.x;
    const int bid = blockIdx.x;

    // ======================= Phase 1: convs + pool (2 tiles) ==================
    {
        float* xs   = (float*)smem;      // [c][r2(2)][col(32)]        4096
        float* pw   = xs + 4096;         // [(c4*32 + o)*4 + j]        2048
        float* fw   = pw + 2048;         //                            2048
        float* wt_l = fw + 2048;         //                              64

        // stage weights once (tile-independent)
        for (int idx = tid; idx < 2048; idx += 256) {
            const int c4 = idx >> 7, o = (idx >> 2) & 31, j = idx & 3;
            pw[idx] = psi_w[o * 64 + 4 * c4 + j];
            fw[idx] = phi_w[o * 64 + 4 * c4 + j];
        }
        if (tid < 64) {
            float acc = 0.f;
            for (int o2 = 0; o2 < 32; ++o2)
                acc += h0_w[o2] * theta_w[o2 * 64 + tid];
            wt_l[tid] = acc;
        }

        const float h20 = h2_w[0], h21 = h2_w[1];

        for (int half = 0; half < 2; ++half) {
            const int u = 2 * bid + half;          // tile unit [0,512)
            const int b = u >> 7;
            const int rem = u & 127;
            const int fh = rem >> 2;               // [0,32)
            const int q = rem & 3;                 // col-quarter [0,4)
            const int c0 = q * 32;

            __syncthreads();   // weights staged / prev tile's xs readers done

            // stage x tile (float4): 64 ch x rows {2fh,2fh+1} x cols [c0,c0+32)
            for (int idx = tid; idx < 1024; idx += 256) {
                const int c = idx >> 4, r2 = (idx >> 3) & 1, t4 = idx & 7;
                const float4 v = *(const float4*)&x[(((size_t)b * 64 + c) * 64 + (2 * fh + r2)) * 128 + c0 + 4 * t4];
                *(float4*)&xs[c * 64 + r2 * 32 + 4 * t4] = v;
            }
            __syncthreads();

            // conv + pool: thread=(o in [0,32), g in [0,8)); half-cols 2g, 2g+1
            {
                const int o = tid & 31, g = tid >> 5;
                const float pb = psi_b[o], fb = phi_b[o], h1 = h1_w[o];
                const float4* pw4 = (const float4*)pw;
                const float4* fw4 = (const float4*)fw;
                const float4* xs4 = (const float4*)xs;
                float sp[2][4] = {{0,0,0,0},{0,0,0,0}};
                float sf[2][4] = {{0,0,0,0},{0,0,0,0}};
                for (int c4 = 0; c4 < 16; ++c4) {
                    const float4 pv = pw4[c4 * 32 + o];    // b128, consecutive per lane
                    const float4 fv = fw4[c4 * 32 + o];
                    const float* pvf = (const float*)&pv;
                    const float* fvf = (const float*)&fv;
#pragma unroll
                    for (int j = 0; j < 4; ++j) {
                        const int c = 4 * c4 + j;
                        const float4 r0 = xs4[c * 16 + g];       // broadcast (2 addr/wave)
                        const float4 r1 = xs4[c * 16 + 8 + g];
                        const float wp = pvf[j], wf = fvf[j];
                        sp[0][0] += wp * r0.x; sp[0][1] += wp * r0.y;
                        sp[0][2] += wp * r1.x; sp[0][3] += wp * r1.y;
                        sp[1][0] += wp * r0.z; sp[1][1] += wp * r0.w;
                        sp[1][2] += wp * r1.z; sp[1][3] += wp * r1.w;
                        sf[0][0] += wf * r0.x; sf[0][1] += wf * r0.y;
                        sf[0][2] += wf * r1.x; sf[0][3] += wf * r1.y;
                        sf[1][0] += wf * r0.z; sf[1][1] += wf * r0.w;
                        sf[1][2] += wf * r1.z; sf[1][3] += wf * r1.w;
                    }
                }
#pragma unroll
                for (int h = 0; h < 2; ++h) {
                    const int hc = 2 * g + h;
                    const float psiv = fmaxf(fmaxf(sp[h][0], sp[h][1]), fmaxf(sp[h][2], sp[h][3])) + pb;
                    const float phiv = fmaxf(fmaxf(sf[h][0], sf[h][1]), fmaxf(sf[h][2], sf[h][3])) + fb;
                    const int m = fh * 64 + q * 16 + hc;
                    ws[OFF_PSI2 + ((size_t)b * 2048 + m) * 32 + o] = psiv;
                    float tv = h1 * phiv;
                    for (int mask = 1; mask < 32; mask <<= 1)
                        tv += __shfl_xor(tv, mask, 64);
                    if (o == 0) {
                        const float bpos = h20 * (fh * (1.0f / 31.0f))
                                         + h21 * ((q * 16 + hc) * (1.0f / 63.0f));
                        ws[OFF_V + b * 2048 + m] = tv - bpos;
                    }
                }
            }

            // u[b,n] for the 64 full positions of this tile
            if (tid < 64) {
                const int r2 = tid >> 5, tl = tid & 31;
                float acc = 0.f;
                for (int c = 0; c < 64; ++c)
                    acc += xs[c * 64 + r2 * 32 + tl] * wt_l[c];
                float tb_ = 0.f;
                for (int o2 = 0; o2 < 32; ++o2)
                    tb_ += h0_w[o2] * theta_b[o2];
                const int f = 2 * fh + r2, tt = c0 + tl;
                const int n = f * 128 + tt;
                const float a = h20 * (f * (1.0f / 63.0f)) + h21 * (tt * (1.0f / 127.0f));
                ws[OFF_U + b * 8192 + n] = acc + tb_ + a;
            }
        }
    }

    grid_barrier(tid);

    // ======================= Phase 2: rank sort (2 chunks, same b) ============
    {
        float* vl = (float*)smem;                 // 2048
        int* part = (int*)(vl + 2048);            // 256

        const int u0 = 2 * bid;
        const int b = u0 >> 7;
        const float* v = ws + OFF_V + b * 2048;
        for (int i = tid; i < 2048; i += 256) vl[i] = v[i];
        __syncthreads();

        const float4* v4 = (const float4*)vl;
        for (int half = 0; half < 2; ++half) {
            const int chunk = (u0 & 127) + half;
            const int ml = tid >> 4;        // m within chunk [0,16)
            const int jq = tid & 15;        // j-segment [0,16)
            const int m = chunk * 16 + ml;
            const float vm = vl[m];
            int cnt = 0;
#pragma unroll 4
            for (int i = 0; i < 32; ++i) {
                const int j4 = jq + 16 * i;          // wave reads consecutive float4s
                const float4 vv = v4[j4];
                const int jb = j4 * 4;
                cnt += (vv.x > vm) || (vv.x == vm && (jb    ) < m);
                cnt += (vv.y > vm) || (vv.y == vm && (jb + 1) < m);
                cnt += (vv.z > vm) || (vv.z == vm && (jb + 2) < m);
                cnt += (vv.w > vm) || (vv.w == vm && (jb + 3) < m);
            }
            part[tid] = cnt;
            __syncthreads();
            if (tid < 16) {
                int r = 0;
#pragma unroll
                for (int j = 0; j < 16; ++j) r += part[tid * 16 + j];
                ws[OFF_VS + b * 2048 + r] = vl[chunk * 16 + tid];
                g_perm[b * 2048 + r] = chunk * 16 + tid;
            }
            __syncthreads();   // part[] reuse next half
        }
    }

    grid_barrier(tid);

    // ======================= Phase 3: z + scan -> Q01 =========================
    {
        float* Wrow = (float*)smem;      // 32
        float* wt0  = Wrow + 32;         // 4
        float* wt1  = wt0 + 4;           // 4

        const int b = bid >> 6, o = bid & 63;
        if (tid < 32) Wrow[tid] = W_w[o * 33 + tid];   // W_w is (64,33); col 32 = zero channel
        __syncthreads();

        const int* perm = g_perm + b * 2048;
        const float* vs = ws + OFF_VS + b * 2048;
        const float* psi2 = ws + OFF_PSI2 + (size_t)b * 2048 * 32;

        float zl[8], vlv[8];
        float s0 = 0.f, s1 = 0.f;
        const int base = tid * 8;
#pragma unroll
        for (int qq = 0; qq < 8; ++qq) {
            const int i = base + qq;
            const int mp = perm[i];
            const float4* pr = (const float4*)(psi2 + (size_t)mp * 32);
            float z = 0.f;
#pragma unroll
            for (int w = 0; w < 8; ++w) {
                const float4 p4 = pr[w];
                z += Wrow[4 * w] * p4.x + Wrow[4 * w + 1] * p4.y
                   + Wrow[4 * w + 2] * p4.z + Wrow[4 * w + 3] * p4.w;
            }
            const float vv = vs[i];
            zl[qq] = z; vlv[qq] = vv;
            s0 += z; s1 += vv * z;
        }

        // inclusive wave scan (64 lanes) of per-thread sums
        float w0 = s0, w1 = s1;
        const int lane = tid & 63, wv = tid >> 6;
#pragma unroll
        for (int off = 1; off < 64; off <<= 1) {
            const float t0_ = __shfl_up(w0, off, 64);
            const float t1_ = __shfl_up(w1, off, 64);
            if (lane >= off) { w0 += t0_; w1 += t1_; }
        }
        if (lane == 63) { wt0[wv] = w0; wt1[wv] = w1; }
        __syncthreads();
        float base0 = 0.f, base1 = 0.f;
        for (int w = 0; w < wv; ++w) { base0 += wt0[w]; base1 += wt1[w]; }
        float r0 = w0 + base0 - s0, r1 = w1 + base1 - s1;   // exclusive prefix

        float2* Q01 = (float2*)(ws + OFF_Q01) + (size_t)b * 2049 * 64;
#pragma unroll
        for (int qq = 0; qq < 8; ++qq) {
            r0 += zl[qq]; r1 += vlv[qq] * zl[qq];
            float2 p; p.x = r0; p.y = r1;
            Q01[(size_t)(base + qq + 1) * 64 + o] = p;
        }
        if (tid == 0) { float2 z2; z2.x = 0.f; z2.y = 0.f; Q01[o] = z2; }
    }

    grid_barrier(tid);

    // ======================= Phase 4: gather + epilogue (2 tiles) =============
    {
        float* vsl   = (float*)smem;             // 2048
        float* tileb = vsl + 2048;               // [o][n] pitch 65 -> 4160
        float* uarr  = tileb + 4160;             // 64
        int*   karr  = (int*)(uarr + 64);        // 64

        const int u0 = 2 * bid;
        const int b = u0 >> 7;

        const float* vs = ws + OFF_VS + b * 2048;
        for (int i = tid; i < 2048; i += 256) vsl[i] = vs[i];   // same b both tiles

        const int lane = tid & 63, w = tid >> 6;   // w in [0,4)
        const float inv = bn_g[lane] * __frsqrt_rn(bn_v[lane] + 1e-5f);
        const float sft = W_b[lane] * inv + bn_b[lane] - bn_m[lane] * inv;
        const float2* Q01 = (const float2*)(ws + OFF_Q01) + (size_t)b * 2049 * 64;
        __syncthreads();

        for (int half = 0; half < 2; ++half) {
            const int tile = (u0 & 127) + half;
            const int n0 = tile * 64;

            if (tid < 64) {
                const float u = ws[OFF_U + b * 8192 + n0 + tid];
                const float thr = -u;
                int lo = 0, hi = 2048;
                while (lo < hi) {                  // first idx with vsl[idx] <= -u (descending)
                    const int mid = (lo + hi) >> 1;
                    if (vsl[mid] > thr) lo = mid + 1; else hi = mid;
                }
                karr[tid] = lo;
                uarr[tid] = u;
            }
            __syncthreads();

            for (int nl = w; nl < 64; nl += 4) {
                const int k = karr[nl];
                const float u = uarr[nl];
                const float2 qv = Q01[(size_t)k * 64 + lane];  // 512B coalesced row
                const float raw = (u * qv.x + qv.y) * (1.0f / 2048.0f);
                tileb[lane * 65 + nl] = raw * inv + sft;       // 2-way bank aliasing: free
            }
            __syncthreads();

            for (int idx = tid; idx < 2048; idx += 256) {      // float2 epilogue
                const int o = idx >> 5, j2 = idx & 31;
                const size_t gi = ((size_t)b * 64 + o) * 8192 + n0 + 2 * j2;
                const float2 xv = *(const float2*)&x[gi];
                float2 r;
                r.x = tileb[o * 65 + 2 * j2] + xv.x;
                r.y = tileb[o * 65 + 2 * j2 + 1] + xv.y;
                *(float2*)&out[gi] = r;
            }
            __syncthreads();   // karr/tileb reuse next half
        }
    }
}

// ---------------------------------------------------------------------------
extern "C" void kernel_launch(void* const* d_in, const int* in_sizes, int n_in,
                              void* d_out, int out_size, void* d_ws, size_t ws_size,
                              hipStream_t stream)
{
    (void)in_sizes; (void)n_in; (void)out_size; (void)d_ws; (void)ws_size;
    const float* x       = (const float*)d_in[0];
    const float* psi_w   = (const float*)d_in[1];
    const float* psi_b   = (const float*)d_in[2];
    const float* theta_w = (const float*)d_in[3];
    const float* theta_b = (const float*)d_in[4];
    const float* phi_w   = (const float*)d_in[5];
    const float* phi_b   = (const float*)d_in[6];
    const float* h0_w    = (const float*)d_in[7];
    const float* h1_w    = (const float*)d_in[8];
    const float* h2_w    = (const float*)d_in[9];
    const float* W_w     = (const float*)d_in[10];
    const float* W_b     = (const float*)d_in[11];
    const float* bn_g    = (const float*)d_in[12];
    const float* bn_b    = (const float*)d_in[13];
    const float* bn_m    = (const float*)d_in[14];
    const float* bn_v    = (const float*)d_in[15];
    float* out = (float*)d_out;

    fused<<<dim3(GRID_), dim3(256), 0, stream>>>(
        x, psi_w, psi_b, theta_w, theta_b, phi_w, phi_b,
        h0_w, h1_w, h2_w, W_w, W_b, bn_g, bn_b, bn_m, bn_v, out);
}

// Round 5
// 120.221 us; speedup vs baseline: 2.5541x; 1.5694x over previous
//
#include <hip/hip_runtime.h>

// Problem constants
#define B_ 4
#define C_ 64
#define F_ 64
#define T_ 128
#define IC_ 32
#define N_ 8192
#define M_ 2048

// Scratch layout (float units; all fp32 intermediates)
// NOTE vs earlier rounds: psi2 is GONE (z computed in k1); z replaces it.
#define OFF_U      0           // B*N                        (32768)
#define OFF_Z      32768       // B*M*64, layout [b][m][o]   (524288)
#define OFF_V      557056      // B*M
#define OFF_VS     565248      // B*M sorted v (descending)
#define OFF_Q01    573440      // B*2049*64 float2 (z-prefix, vz-prefix), [b][k][o]
#define WS_FLOATS  1622528     // 6.49 MB static device scratch

__device__ __align__(16) float g_ws[WS_FLOATS];
__device__ int g_perm[B_ * M_];

// ---------------------------------------------------------------------------
// Kernel 1: psi/phi conv + 2x2 maxpool; z = W_w . psi folded IN-KERNEL (psi
// never leaves the block); collapsed theta -> u; v from phi.
// 512 blocks x 256 thr. block=(b, fh, col-quarter). LDS ~43 KB -> 2 blk/CU.
// z write is lane-coalesced 256B ([b][m][o], o = lane).
// ---------------------------------------------------------------------------
__global__ __launch_bounds__(256) void k1(
    const float* __restrict__ x,
    const float* __restrict__ psi_w, const float* __restrict__ psi_b,
    const float* __restrict__ theta_w, const float* __restrict__ theta_b,
    const float* __restrict__ phi_w, const float* __restrict__ phi_b,
    const float* __restrict__ h0_w, const float* __restrict__ h1_w,
    const float* __restrict__ h2_w, const float* __restrict__ W_w)
{
    float* __restrict__ ws = g_ws;
    __shared__ __align__(16) float xs[4096];   // [c][r2(2)][col(32)]
    __shared__ __align__(16) float pw[2048];   // psi_w [(c4*32 + o)*4 + j]
    __shared__ __align__(16) float fw[2048];   // phi_w same layout
    __shared__ __align__(16) float Wl[2048];   // W_w   [(c4*64 + o64)*4 + j]
    __shared__ __align__(16) float pt[512];    // psi tile [m_local(16)][c(32)]
    __shared__ float wt_l[64];

    const int tid = threadIdx.x;
    const int bid = blockIdx.x;
    const int b = bid >> 7;
    const int rem = bid & 127;
    const int fh = rem >> 2;        // [0,32)
    const int q = rem & 3;          // col-quarter [0,4)
    const int c0 = q * 32;

    // stage x tile (float4): 64 ch x rows {2fh,2fh+1} x cols [c0,c0+32)
    for (int idx = tid; idx < 1024; idx += 256) {
        const int c = idx >> 4, r2 = (idx >> 3) & 1, t4 = idx & 7;
        const float4 v = *(const float4*)&x[(((size_t)b * 64 + c) * 64 + (2 * fh + r2)) * 128 + c0 + 4 * t4];
        *(float4*)&xs[c * 64 + r2 * 32 + 4 * t4] = v;
    }
    // stage conv weights (float4-grouped) + W_w rows (cols 0..31; col 32 is
    // the zero structure channel and drops out of z)
    for (int idx = tid; idx < 2048; idx += 256) {
        const int c4 = idx >> 7, o = (idx >> 2) & 31, j = idx & 3;
        pw[idx] = psi_w[o * 64 + 4 * c4 + j];
        fw[idx] = phi_w[o * 64 + 4 * c4 + j];
        const int c4w = idx >> 8, o64 = (idx >> 2) & 63, jw = idx & 3;
        Wl[idx] = W_w[o64 * 33 + 4 * c4w + jw];
    }
    if (tid < 64) {
        float acc = 0.f;
        for (int o2 = 0; o2 < 32; ++o2)
            acc += h0_w[o2] * theta_w[o2 * 64 + tid];
        wt_l[tid] = acc;
    }
    __syncthreads();

    const float h20 = h2_w[0], h21 = h2_w[1];

    // conv + pool: thread=(o in [0,32), g in [0,8)); half-cols 2g, 2g+1
    {
        const int o = tid & 31, g = tid >> 5;
        const float pb = psi_b[o], fb = phi_b[o], h1 = h1_w[o];
        const float4* pw4 = (const float4*)pw;
        const float4* fw4 = (const float4*)fw;
        const float4* xs4 = (const float4*)xs;
        float sp[2][4] = {{0,0,0,0},{0,0,0,0}};
        float sf[2][4] = {{0,0,0,0},{0,0,0,0}};
        for (int c4 = 0; c4 < 16; ++c4) {
            const float4 pv = pw4[c4 * 32 + o];    // b128, consecutive per lane
            const float4 fv = fw4[c4 * 32 + o];
            const float* pvf = (const float*)&pv;
            const float* fvf = (const float*)&fv;
#pragma unroll
            for (int j = 0; j < 4; ++j) {
                const int c = 4 * c4 + j;
                const float4 r0 = xs4[c * 16 + g];       // broadcast (2 addr/wave)
                const float4 r1 = xs4[c * 16 + 8 + g];
                const float wp = pvf[j], wf = fvf[j];
                sp[0][0] += wp * r0.x; sp[0][1] += wp * r0.y;
                sp[0][2] += wp * r1.x; sp[0][3] += wp * r1.y;
                sp[1][0] += wp * r0.z; sp[1][1] += wp * r0.w;
                sp[1][2] += wp * r1.z; sp[1][3] += wp * r1.w;
                sf[0][0] += wf * r0.x; sf[0][1] += wf * r0.y;
                sf[0][2] += wf * r1.x; sf[0][3] += wf * r1.y;
                sf[1][0] += wf * r0.z; sf[1][1] += wf * r0.w;
                sf[1][2] += wf * r1.z; sf[1][3] += wf * r1.w;
            }
        }
#pragma unroll
        for (int h = 0; h < 2; ++h) {
            const int hc = 2 * g + h;
            const float psiv = fmaxf(fmaxf(sp[h][0], sp[h][1]), fmaxf(sp[h][2], sp[h][3])) + pb;
            const float phiv = fmaxf(fmaxf(sf[h][0], sf[h][1]), fmaxf(sf[h][2], sf[h][3])) + fb;
            const int m = fh * 64 + q * 16 + hc;
            pt[hc * 32 + o] = psiv;               // LDS only — psi2 never global
            float tv = h1 * phiv;
            for (int mask = 1; mask < 32; mask <<= 1)
                tv += __shfl_xor(tv, mask, 64);
            if (o == 0) {
                const float bpos = h20 * (fh * (1.0f / 31.0f))
                                 + h21 * ((q * 16 + hc) * (1.0f / 63.0f));
                ws[OFF_V + b * 2048 + m] = tv - bpos;
            }
        }
    }
    __syncthreads();   // pt complete

    // z[b][m][o'] = sum_c W_w[o'][c] * pt[m_local][c]  (thread = (o'=lane, mseg))
    {
        const int op = tid & 63, mseg = tid >> 6;   // wave-uniform mseg
        const float4* Wl4 = (const float4*)Wl;
        const float4* pt4 = (const float4*)pt;
        float4 wreg[8];
#pragma unroll
        for (int c4 = 0; c4 < 8; ++c4)
            wreg[c4] = Wl4[c4 * 64 + op];           // b128 lane-consecutive
#pragma unroll
        for (int j = 0; j < 4; ++j) {
            const int ml = mseg * 4 + j;
            float acc = 0.f;
#pragma unroll
            for (int c4 = 0; c4 < 8; ++c4) {
                const float4 pv = pt4[ml * 8 + c4]; // broadcast (1 addr/wave)
                acc += wreg[c4].x * pv.x + wreg[c4].y * pv.y
                     + wreg[c4].z * pv.z + wreg[c4].w * pv.w;
            }
            const int m = fh * 64 + q * 16 + ml;
            ws[OFF_Z + ((size_t)b * 2048 + m) * 64 + op] = acc;  // 256B coalesced
        }
    }

    // u[b,n] for the 64 full positions of this tile
    if (tid < 64) {
        const int r2 = tid >> 5, tl = tid & 31;
        float acc = 0.f;
        for (int c = 0; c < 64; ++c)
            acc += xs[c * 64 + r2 * 32 + tl] * wt_l[c];
        float tb_ = 0.f;
        for (int o2 = 0; o2 < 32; ++o2)
            tb_ += h0_w[o2] * theta_b[o2];
        const int f = 2 * fh + r2, tt = c0 + tl;
        const int n = f * 128 + tt;
        const float a = h20 * (f * (1.0f / 63.0f)) + h21 * (tt * (1.0f / 127.0f));
        ws[OFF_U + b * 8192 + n] = acc + tb_ + a;
    }
}

// ---------------------------------------------------------------------------
// Kernel 2: barrier-free rank sort (descending, index tie-break)
// 512 blocks x 256 thr. block=(b, chunk of 16 m's). Conflict-free strided walk.
// ---------------------------------------------------------------------------
__global__ __launch_bounds__(256) void k2()
{
    float* __restrict__ ws = g_ws;
    __shared__ __align__(16) float vl[2048];
    __shared__ int part[256];
    const int tid = threadIdx.x;
    const int b = blockIdx.x >> 7, chunk = blockIdx.x & 127;
    const float* v = ws + OFF_V + b * 2048;
    for (int i = tid; i < 2048; i += 256) vl[i] = v[i];
    __syncthreads();

    const int ml = tid >> 4;        // m within chunk [0,16)
    const int jq = tid & 15;        // j-segment [0,16)
    const int m = chunk * 16 + ml;
    const float vm = vl[m];
    int cnt = 0;
    const float4* v4 = (const float4*)vl;
#pragma unroll 4
    for (int i = 0; i < 32; ++i) {
        const int j4 = jq + 16 * i;          // wave reads consecutive float4s
        const float4 vv = v4[j4];
        const int jb = j4 * 4;
        cnt += (vv.x > vm) || (vv.x == vm && (jb    ) < m);
        cnt += (vv.y > vm) || (vv.y == vm && (jb + 1) < m);
        cnt += (vv.z > vm) || (vv.z == vm && (jb + 2) < m);
        cnt += (vv.w > vm) || (vv.w == vm && (jb + 3) < m);
    }
    part[tid] = cnt;
    __syncthreads();
    if (tid < 16) {
        int r = 0;
#pragma unroll
        for (int j = 0; j < 16; ++j) r += part[tid * 16 + j];
        ws[OFF_VS + b * 2048 + r] = vl[chunk * 16 + tid];
        g_perm[b * 2048 + r] = chunk * 16 + tid;
    }
}

// ---------------------------------------------------------------------------
// Kernel 3: gather precomputed z (4B/item, was a 128B psi2 row), scan ->
// Q01[b][k][o] (float2). 256 blocks (b,o) x 512 thr, 4 items/thr.
// ---------------------------------------------------------------------------
__global__ __launch_bounds__(512) void k3()
{
    float* __restrict__ ws = g_ws;
    __shared__ float wt0[8], wt1[8];
    const int tid = threadIdx.x;
    const int b = blockIdx.x >> 6, o = blockIdx.x & 63;

    const int* perm = g_perm + b * 2048;
    const float* vs = ws + OFF_VS + b * 2048;
    const float* zg = ws + OFF_Z + (size_t)b * 2048 * 64 + o;

    float zl[4], vlv[4];
    float s0 = 0.f, s1 = 0.f;
    const int base = tid * 4;
#pragma unroll
    for (int qq = 0; qq < 4; ++qq) {
        const int i = base + qq;
        const int mp = perm[i];
        const float z = zg[(size_t)mp * 64];    // scattered 4B, L2-resident
        const float vv = vs[i];
        zl[qq] = z; vlv[qq] = vv;
        s0 += z; s1 += vv * z;
    }

    // inclusive wave scan (64 lanes) of per-thread sums
    float w0 = s0, w1 = s1;
    const int lane = tid & 63, wv = tid >> 6;
#pragma unroll
    for (int off = 1; off < 64; off <<= 1) {
        const float t0_ = __shfl_up(w0, off, 64);
        const float t1_ = __shfl_up(w1, off, 64);
        if (lane >= off) { w0 += t0_; w1 += t1_; }
    }
    if (lane == 63) { wt0[wv] = w0; wt1[wv] = w1; }
    __syncthreads();
    float base0 = 0.f, base1 = 0.f;
    for (int w = 0; w < wv; ++w) { base0 += wt0[w]; base1 += wt1[w]; }
    float r0 = w0 + base0 - s0, r1 = w1 + base1 - s1;   // exclusive prefix

    float2* Q01 = (float2*)(ws + OFF_Q01) + (size_t)b * 2049 * 64;
#pragma unroll
    for (int qq = 0; qq < 4; ++qq) {
        r0 += zl[qq]; r1 += vlv[qq] * zl[qq];
        float2 p; p.x = r0; p.y = r1;
        Q01[(size_t)(base + qq + 1) * 64 + o] = p;
    }
    if (tid == 0) { float2 z2; z2.x = 0.f; z2.y = 0.f; Q01[o] = z2; }
}

// ---------------------------------------------------------------------------
// Kernel 4: stage sorted v in LDS (float4), binary search k(n), gather Q01
// rows (one dwordx2 per (n,lane)), fold W_b+BN, LDS transpose, add x, store.
// 512 blocks x 512 thr (16 waves/CU).
// ---------------------------------------------------------------------------
__global__ __launch_bounds__(512) void k4(
    const float* __restrict__ x,
    const float* __restrict__ W_b,
    const float* __restrict__ bn_g, const float* __restrict__ bn_b,
    const float* __restrict__ bn_m, const float* __restrict__ bn_v,
    float* __restrict__ out)
{
    const float* __restrict__ ws = g_ws;
    __shared__ __align__(16) float vsl[2048];
    __shared__ float tileb[64 * 65];   // [o][n] pitch 65
    __shared__ int karr[64];
    __shared__ float uarr[64];

    const int tid = threadIdx.x;
    const int b = blockIdx.x >> 7, tile = blockIdx.x & 127;
    const int n0 = tile * 64;

    const float* vs = ws + OFF_VS + b * 2048;
    *(float4*)&vsl[tid * 4] = *(const float4*)&vs[tid * 4];   // 512 thr x 16B
    __syncthreads();

    if (tid < 64) {
        const float u = ws[OFF_U + b * 8192 + n0 + tid];
        const float thr = -u;
        int lo = 0, hi = 2048;
        while (lo < hi) {                  // first idx with vsl[idx] <= -u (descending)
            const int mid = (lo + hi) >> 1;
            if (vsl[mid] > thr) lo = mid + 1; else hi = mid;
        }
        karr[tid] = lo;
        uarr[tid] = u;
    }
    __syncthreads();

    const int lane = tid & 63, w = tid >> 6;   // w in [0,8)
    const float inv = bn_g[lane] * __frsqrt_rn(bn_v[lane] + 1e-5f);
    const float sft = W_b[lane] * inv + bn_b[lane] - bn_m[lane] * inv;
    const float2* Q01 = (const float2*)(ws + OFF_Q01) + (size_t)b * 2049 * 64;

    for (int nl = w; nl < 64; nl += 8) {
        const int k = karr[nl];
        const float u = uarr[nl];
        const float2 qv = Q01[(size_t)k * 64 + lane];  // 512B coalesced row
        const float raw = (u * qv.x + qv.y) * (1.0f / 2048.0f);
        tileb[lane * 65 + nl] = raw * inv + sft;       // 2-way bank aliasing: free
    }
    __syncthreads();

    for (int idx = tid; idx < 2048; idx += 512) {      // float2 epilogue
        const int o = idx >> 5, j2 = idx & 31;
        const size_t gi = ((size_t)b * 64 + o) * 8192 + n0 + 2 * j2;
        const float2 xv = *(const float2*)&x[gi];
        float2 r;
        r.x = tileb[o * 65 + 2 * j2] + xv.x;
        r.y = tileb[o * 65 + 2 * j2 + 1] + xv.y;
        *(float2*)&out[gi] = r;
    }
}

// ---------------------------------------------------------------------------
extern "C" void kernel_launch(void* const* d_in, const int* in_sizes, int n_in,
                              void* d_out, int out_size, void* d_ws, size_t ws_size,
                              hipStream_t stream)
{
    (void)in_sizes; (void)n_in; (void)out_size; (void)d_ws; (void)ws_size;
    const float* x       = (const float*)d_in[0];
    const float* psi_w   = (const float*)d_in[1];
    const float* psi_b   = (const float*)d_in[2];
    const float* theta_w = (const float*)d_in[3];
    const float* theta_b = (const float*)d_in[4];
    const float* phi_w   = (const float*)d_in[5];
    const float* phi_b   = (const float*)d_in[6];
    const float* h0_w    = (const float*)d_in[7];
    const float* h1_w    = (const float*)d_in[8];
    const float* h2_w    = (const float*)d_in[9];
    const float* W_w     = (const float*)d_in[10];
    const float* W_b     = (const float*)d_in[11];
    const float* bn_g    = (const float*)d_in[12];
    const float* bn_b    = (const float*)d_in[13];
    const float* bn_m    = (const float*)d_in[14];
    const float* bn_v    = (const float*)d_in[15];
    float* out = (float*)d_out;

    k1<<<dim3(512), dim3(256), 0, stream>>>(x, psi_w, psi_b, theta_w, theta_b,
                                            phi_w, phi_b, h0_w, h1_w, h2_w, W_w);
    k2<<<dim3(512), dim3(256), 0, stream>>>();
    k3<<<dim3(256), dim3(512), 0, stream>>>();
    k4<<<dim3(512), dim3(512), 0, stream>>>(x, W_b, bn_g, bn_b, bn_m, bn_v, out);
}

// Round 6
// 113.489 us; speedup vs baseline: 2.7056x; 1.0593x over previous
//
#include <hip/hip_runtime.h>

// Problem constants
#define B_ 4
#define C_ 64
#define F_ 64
#define T_ 128
#define IC_ 32
#define N_ 8192
#define M_ 2048

// Scratch layout (float units; all fp32 intermediates)
// z layout is [b][o][m] (MFMA-store friendly; k3 gathers within an 8KB row)
#define OFF_U      0           // B*N                        (32768)
#define OFF_Z      32768       // B*64*M, layout [b][o][m]   (524288)
#define OFF_V      557056      // B*M
#define OFF_VS     565248      // B*M sorted v (descending)
#define OFF_Q01    573440      // B*2049*64 float2 (z-prefix, vz-prefix), [b][k][o]
#define WS_FLOATS  1622528     // 6.49 MB static device scratch

__device__ __align__(16) float g_ws[WS_FLOATS];
__device__ int g_perm[B_ * M_];

typedef __attribute__((ext_vector_type(8))) short short8_t;
typedef __attribute__((ext_vector_type(4))) float f32x4;

__device__ __forceinline__ unsigned short f2bf(float f) {
    unsigned b = __float_as_uint(f);
    b += 0x7fffu + ((b >> 16) & 1u);        // RNE
    return (unsigned short)(b >> 16);
}
__device__ __forceinline__ float bf2f(unsigned short h) {
    return __uint_as_float(((unsigned)h) << 16);
}

// Swizzled LDS index helpers (indices in shorts; XOR bits >= 8-short granule,
// so b64/b128 blocks stay contiguous). T2-style: breaks the 16-way bank
// conflict of 128B-stride rows read column-wise by lanes 0..15.
#define XSIDX(p, c)  ((((p) * 64) + (c)) ^ (((p) & 7) << 3))    // [128][64] bf16
#define WAIDX(o, c)  ((((o) * 64) + (c)) ^ (((o) & 7) << 3))    // [64][64]  bf16
#define WZIDX(o, c)  ((((o) * 32) + (c)) ^ (((o) & 3) << 3))    // [64][32]  bf16
#define PSIDX(p, c)  ((((p) * 32) + (c)) ^ (((p) & 3) << 3))    // [32][32]  bf16

// ---------------------------------------------------------------------------
// Kernel 1 (MFMA rewrite): psi/phi conv as bf16 MFMA + in-register 2x2 pool;
// z = W_w . psi as a second MFMA; v from phi via shuffles; u from bf16 tile.
// 256 blocks x 256 thr (4 waves). Block = (b, row-pair fh, col-half hf):
// 2 img rows x 64 cols = 128 positions. LDS ~31 KB.
// Old k1 was LDS-issue-bound (~200 ds_read_b128/thread); this is ~60.
// ---------------------------------------------------------------------------
__global__ __launch_bounds__(256) void k1(
    const float* __restrict__ x,
    const float* __restrict__ psi_w, const float* __restrict__ psi_b,
    const float* __restrict__ theta_w, const float* __restrict__ theta_b,
    const float* __restrict__ phi_w, const float* __restrict__ phi_b,
    const float* __restrict__ h0_w, const float* __restrict__ h1_w,
    const float* __restrict__ h2_w, const float* __restrict__ W_w)
{
    float* __restrict__ ws = g_ws;
    __shared__ __align__(16) unsigned short XS[128 * 64];  // x tile bf16 [p][c]
    __shared__ __align__(16) unsigned short WA[64 * 64];   // [psi_w; phi_w] bf16 [o][c]
    __shared__ __align__(16) unsigned short WZ[64 * 32];   // W_w cols 0..31 bf16 [o64][ic]
    __shared__ __align__(16) unsigned short PS[32 * 32];   // pooled psi bf16 [pc][ic]
    __shared__ __align__(16) float pb[64];                 // psi_b | phi_b
    __shared__ __align__(16) float h1l[32];
    __shared__ __align__(16) float wtl[64];                // sum_o h0[o]*theta_w[o][c]
    __shared__ float vtmp[2][32];

    const int tid = threadIdx.x;
    const int bid = blockIdx.x;
    const int b = bid >> 6;
    const int rem = bid & 63;
    const int fh = rem >> 1;        // row-pair [0,32)
    const int hf = rem & 1;         // col-half

    const float h20 = h2_w[0], h21 = h2_w[1];

    // ---- stage x tile: f32 -> bf16, 4x4 in-register transpose -> [p][c] ----
    for (int it = 0; it < 2; ++it) {
        const int u = it * 256 + tid;          // unit in [0,512)
        const int colq = u & 15, r = (u >> 4) & 1, cq = u >> 5;
        float4 xv[4];
#pragma unroll
        for (int j = 0; j < 4; ++j)
            xv[j] = *(const float4*)&x[(((size_t)b * 64 + (4 * cq + j)) * 64 + (2 * fh + r)) * 128 + hf * 64 + 4 * colq];
        const float* xf0 = (const float*)&xv[0];
        const float* xf1 = (const float*)&xv[1];
        const float* xf2 = (const float*)&xv[2];
        const float* xf3 = (const float*)&xv[3];
#pragma unroll
        for (int i = 0; i < 4; ++i) {
            const int p = r * 64 + 4 * colq + i;
            short4 sv;
            sv.x = (short)f2bf(xf0[i]); sv.y = (short)f2bf(xf1[i]);
            sv.z = (short)f2bf(xf2[i]); sv.w = (short)f2bf(xf3[i]);
            *(short4*)&XS[XSIDX(p, 4 * cq)] = sv;
        }
    }
    // ---- stage conv weights bf16 [o][c]: rows 0-31 psi, 32-63 phi ----
    for (int it = 0; it < 4; ++it) {
        const int f4 = it * 256 + tid;         // [0,1024)
        const int o2 = f4 >> 4;                // [0,64)
        const int cq = f4 & 15;
        const float* src = (o2 < 32) ? &psi_w[o2 * 64 + 4 * cq]
                                     : &phi_w[(o2 - 32) * 64 + 4 * cq];
        const float4 wv = *(const float4*)src;
        short4 sv;
        sv.x = (short)f2bf(wv.x); sv.y = (short)f2bf(wv.y);
        sv.z = (short)f2bf(wv.z); sv.w = (short)f2bf(wv.w);
        *(short4*)&WA[WAIDX(o2, 4 * cq)] = sv;
    }
    // ---- stage W_w (64x33, cols 0..31) bf16 [o64][ic] (scalar: rows unaligned) ----
    for (int it = 0; it < 8; ++it) {
        const int e = it * 256 + tid;          // [0,2048)
        const int o64 = e >> 5, ic = e & 31;
        WZ[WZIDX(o64, ic)] = f2bf(W_w[o64 * 33 + ic]);
    }
    if (tid < 64) pb[tid] = (tid < 32) ? psi_b[tid] : phi_b[tid - 32];
    if (tid < 32) h1l[tid] = h1_w[tid];
    if (tid < 64) {
        float acc = 0.f;
        for (int o2 = 0; o2 < 32; ++o2)
            acc += h0_w[o2] * theta_w[o2 * 64 + tid];
        wtl[tid] = acc;
    }
    __syncthreads();

    const int w = tid >> 6, lane = tid & 63;
    const int lo = lane & 15, hi = lane >> 4;

    // ---- conv MFMA: wave w owns output rows 16w..16w+15; 8 pos-tiles, K=64 ----
    short8_t a0 = *(const short8_t*)&WA[WAIDX(16 * w + lo, hi * 8)];
    short8_t a1 = *(const short8_t*)&WA[WAIDX(16 * w + lo, 32 + hi * 8)];
    f32x4 acc[8];
#pragma unroll
    for (int t = 0; t < 8; ++t) { acc[t].x = 0.f; acc[t].y = 0.f; acc[t].z = 0.f; acc[t].w = 0.f; }
#pragma unroll
    for (int t = 0; t < 8; ++t) {
        const short8_t b0 = *(const short8_t*)&XS[XSIDX(16 * t + lo, hi * 8)];
        const short8_t b1 = *(const short8_t*)&XS[XSIDX(16 * t + lo, 32 + hi * 8)];
        acc[t] = __builtin_amdgcn_mfma_f32_16x16x32_bf16(a0, b0, acc[t], 0, 0, 0);
        acc[t] = __builtin_amdgcn_mfma_f32_16x16x32_bf16(a1, b1, acc[t], 0, 0, 0);
    }

    // ---- 2x2 maxpool in-register: rows = tiles (t, t+4), cols via shfl_xor 1.
    //      C/D layout: col p = lane&15, row o = hi*4 + r (m89-verified). ----
    const int isPsi = (w < 2);
    const int obase = (w & 1) * 16 + hi * 4;   // channel quad base within 32
    const int pcj = lo >> 1;
#pragma unroll
    for (int t = 0; t < 4; ++t) {
        const int pc = 8 * t + pcj;
        float pv[4];
#pragma unroll
        for (int r = 0; r < 4; ++r) {
            const float mx = fmaxf(acc[t][r], acc[t + 4][r]);
            pv[r] = fmaxf(mx, __shfl_xor(mx, 1, 64)) + pb[(isPsi ? 0 : 32) + obase + r];
        }
        if (isPsi) {
            if ((lane & 1) == 0) {
                short4 sv;
                sv.x = (short)f2bf(pv[0]); sv.y = (short)f2bf(pv[1]);
                sv.z = (short)f2bf(pv[2]); sv.w = (short)f2bf(pv[3]);
                *(short4*)&PS[PSIDX(pc, obase)] = sv;
            }
        } else {
            float hp = h1l[obase] * pv[0] + h1l[obase + 1] * pv[1]
                     + h1l[obase + 2] * pv[2] + h1l[obase + 3] * pv[3];
            hp += __shfl_xor(hp, 16, 64);
            hp += __shfl_xor(hp, 32, 64);       // sum over this wave's 16 phi-ch
            if (hi == 0 && (lane & 1) == 0)
                vtmp[w - 2][pc] = hp;
        }
    }
    __syncthreads();

    // ---- v finalize (32 threads): v = sum_o h1*phi_pool - bpos ----
    if (tid < 32) {
        const int pc = tid;
        const int m = fh * 64 + hf * 32 + pc;
        const float bpos = h20 * (fh * (1.0f / 31.0f))
                         + h21 * ((hf * 32 + pc) * (1.0f / 63.0f));
        ws[OFF_V + b * 2048 + m] = vtmp[0][pc] + vtmp[1][pc] - bpos;
    }

    // ---- z MFMA: z[o64][pc] = W_w[o64][0..31] . psi[0..31][pc], K=32 ----
    {
        const short8_t az = *(const short8_t*)&WZ[WZIDX(16 * w + lo, hi * 8)];
#pragma unroll
        for (int pt = 0; pt < 2; ++pt) {
            const short8_t bz = *(const short8_t*)&PS[PSIDX(16 * pt + lo, hi * 8)];
            f32x4 zc; zc.x = 0.f; zc.y = 0.f; zc.z = 0.f; zc.w = 0.f;
            zc = __builtin_amdgcn_mfma_f32_16x16x32_bf16(az, bz, zc, 0, 0, 0);
            const int m = fh * 64 + hf * 32 + 16 * pt + lo;
#pragma unroll
            for (int r = 0; r < 4; ++r)
                ws[OFF_Z + ((size_t)b * 64 + 16 * w + hi * 4 + r) * 2048 + m] = zc[r];
        }
    }

    // ---- u: collapsed theta conv from bf16 tile; 2 threads per position ----
    {
        const int ph = tid & 1, p = tid >> 1;
        float ua = 0.f;
#pragma unroll
        for (int c4 = 0; c4 < 8; ++c4) {
            const int c = ph * 32 + c4 * 4;
            const short4 xv = *(const short4*)&XS[XSIDX(p, c)];
            const float4 wv = *(const float4*)&wtl[c];
            ua += wv.x * bf2f((unsigned short)xv.x) + wv.y * bf2f((unsigned short)xv.y)
                + wv.z * bf2f((unsigned short)xv.z) + wv.w * bf2f((unsigned short)xv.w);
        }
        ua += __shfl_xor(ua, 1, 64);
        if (ph == 0) {
            float tb_ = 0.f;
            for (int o2 = 0; o2 < 32; ++o2)
                tb_ += h0_w[o2] * theta_b[o2];
            const int f = 2 * fh + (p >> 6), tt = hf * 64 + (p & 63);
            const int n = f * 128 + tt;
            const float a = h20 * (f * (1.0f / 63.0f)) + h21 * (tt * (1.0f / 127.0f));
            ws[OFF_U + b * 8192 + n] = ua + tb_ + a;
        }
    }
}

// ---------------------------------------------------------------------------
// Kernel 2: barrier-free rank sort (descending, index tie-break) — unchanged
// ---------------------------------------------------------------------------
__global__ __launch_bounds__(256) void k2()
{
    float* __restrict__ ws = g_ws;
    __shared__ __align__(16) float vl[2048];
    __shared__ int part[256];
    const int tid = threadIdx.x;
    const int b = blockIdx.x >> 7, chunk = blockIdx.x & 127;
    const float* v = ws + OFF_V + b * 2048;
    for (int i = tid; i < 2048; i += 256) vl[i] = v[i];
    __syncthreads();

    const int ml = tid >> 4;
    const int jq = tid & 15;
    const int m = chunk * 16 + ml;
    const float vm = vl[m];
    int cnt = 0;
    const float4* v4 = (const float4*)vl;
#pragma unroll 4
    for (int i = 0; i < 32; ++i) {
        const int j4 = jq + 16 * i;
        const float4 vv = v4[j4];
        const int jb = j4 * 4;
        cnt += (vv.x > vm) || (vv.x == vm && (jb    ) < m);
        cnt += (vv.y > vm) || (vv.y == vm && (jb + 1) < m);
        cnt += (vv.z > vm) || (vv.z == vm && (jb + 2) < m);
        cnt += (vv.w > vm) || (vv.w == vm && (jb + 3) < m);
    }
    part[tid] = cnt;
    __syncthreads();
    if (tid < 16) {
        int r = 0;
#pragma unroll
        for (int j = 0; j < 16; ++j) r += part[tid * 16 + j];
        ws[OFF_VS + b * 2048 + r] = vl[chunk * 16 + tid];
        g_perm[b * 2048 + r] = chunk * 16 + tid;
    }
}

// ---------------------------------------------------------------------------
// Kernel 3: gather z ([b][o][m] layout now), scan -> Q01[b][k][o]
// ---------------------------------------------------------------------------
__global__ __launch_bounds__(512) void k3()
{
    float* __restrict__ ws = g_ws;
    __shared__ float wt0[8], wt1[8];
    const int tid = threadIdx.x;
    const int b = blockIdx.x >> 6, o = blockIdx.x & 63;

    const int* perm = g_perm + b * 2048;
    const float* vs = ws + OFF_VS + b * 2048;
    const float* zg = ws + OFF_Z + ((size_t)b * 64 + o) * 2048;   // z row [m]

    float zl[4], vlv[4];
    float s0 = 0.f, s1 = 0.f;
    const int base = tid * 4;
#pragma unroll
    for (int qq = 0; qq < 4; ++qq) {
        const int i = base + qq;
        const int mp = perm[i];
        const float z = zg[mp];                 // scattered 4B in an 8KB row
        const float vv = vs[i];
        zl[qq] = z; vlv[qq] = vv;
        s0 += z; s1 += vv * z;
    }

    float w0 = s0, w1 = s1;
    const int lane = tid & 63, wv = tid >> 6;
#pragma unroll
    for (int off = 1; off < 64; off <<= 1) {
        const float t0_ = __shfl_up(w0, off, 64);
        const float t1_ = __shfl_up(w1, off, 64);
        if (lane >= off) { w0 += t0_; w1 += t1_; }
    }
    if (lane == 63) { wt0[wv] = w0; wt1[wv] = w1; }
    __syncthreads();
    float base0 = 0.f, base1 = 0.f;
    for (int w = 0; w < wv; ++w) { base0 += wt0[w]; base1 += wt1[w]; }
    float r0 = w0 + base0 - s0, r1 = w1 + base1 - s1;

    float2* Q01 = (float2*)(ws + OFF_Q01) + (size_t)b * 2049 * 64;
#pragma unroll
    for (int qq = 0; qq < 4; ++qq) {
        r0 += zl[qq]; r1 += vlv[qq] * zl[qq];
        float2 p; p.x = r0; p.y = r1;
        Q01[(size_t)(base + qq + 1) * 64 + o] = p;
    }
    if (tid == 0) { float2 z2; z2.x = 0.f; z2.y = 0.f; Q01[o] = z2; }
}

// ---------------------------------------------------------------------------
// Kernel 4: binary search k(n), gather Q01 rows, fold W_b+BN, add x — unchanged
// ---------------------------------------------------------------------------
__global__ __launch_bounds__(512) void k4(
    const float* __restrict__ x,
    const float* __restrict__ W_b,
    const float* __restrict__ bn_g, const float* __restrict__ bn_b,
    const float* __restrict__ bn_m, const float* __restrict__ bn_v,
    float* __restrict__ out)
{
    const float* __restrict__ ws = g_ws;
    __shared__ __align__(16) float vsl[2048];
    __shared__ float tileb[64 * 65];
    __shared__ int karr[64];
    __shared__ float uarr[64];

    const int tid = threadIdx.x;
    const int b = blockIdx.x >> 7, tile = blockIdx.x & 127;
    const int n0 = tile * 64;

    const float* vs = ws + OFF_VS + b * 2048;
    *(float4*)&vsl[tid * 4] = *(const float4*)&vs[tid * 4];
    __syncthreads();

    if (tid < 64) {
        const float u = ws[OFF_U + b * 8192 + n0 + tid];
        const float thr = -u;
        int lo = 0, hi = 2048;
        while (lo < hi) {
            const int mid = (lo + hi) >> 1;
            if (vsl[mid] > thr) lo = mid + 1; else hi = mid;
        }
        karr[tid] = lo;
        uarr[tid] = u;
    }
    __syncthreads();

    const int lane = tid & 63, w = tid >> 6;
    const float inv = bn_g[lane] * __frsqrt_rn(bn_v[lane] + 1e-5f);
    const float sft = W_b[lane] * inv + bn_b[lane] - bn_m[lane] * inv;
    const float2* Q01 = (const float2*)(ws + OFF_Q01) + (size_t)b * 2049 * 64;

    for (int nl = w; nl < 64; nl += 8) {
        const int k = karr[nl];
        const float u = uarr[nl];
        const float2 qv = Q01[(size_t)k * 64 + lane];
        const float raw = (u * qv.x + qv.y) * (1.0f / 2048.0f);
        tileb[lane * 65 + nl] = raw * inv + sft;
    }
    __syncthreads();

    for (int idx = tid; idx < 2048; idx += 512) {
        const int o = idx >> 5, j2 = idx & 31;
        const size_t gi = ((size_t)b * 64 + o) * 8192 + n0 + 2 * j2;
        const float2 xv = *(const float2*)&x[gi];
        float2 r;
        r.x = tileb[o * 65 + 2 * j2] + xv.x;
        r.y = tileb[o * 65 + 2 * j2 + 1] + xv.y;
        *(float2*)&out[gi] = r;
    }
}

// ---------------------------------------------------------------------------
extern "C" void kernel_launch(void* const* d_in, const int* in_sizes, int n_in,
                              void* d_out, int out_size, void* d_ws, size_t ws_size,
                              hipStream_t stream)
{
    (void)in_sizes; (void)n_in; (void)out_size; (void)d_ws; (void)ws_size;
    const float* x       = (const float*)d_in[0];
    const float* psi_w   = (const float*)d_in[1];
    const float* psi_b   = (const float*)d_in[2];
    const float* theta_w = (const float*)d_in[3];
    const float* theta_b = (const float*)d_in[4];
    const float* phi_w   = (const float*)d_in[5];
    const float* phi_b   = (const float*)d_in[6];
    const float* h0_w    = (const float*)d_in[7];
    const float* h1_w    = (const float*)d_in[8];
    const float* h2_w    = (const float*)d_in[9];
    const float* W_w     = (const float*)d_in[10];
    const float* W_b     = (const float*)d_in[11];
    const float* bn_g    = (const float*)d_in[12];
    const float* bn_b    = (const float*)d_in[13];
    const float* bn_m    = (const float*)d_in[14];
    const float* bn_v    = (const float*)d_in[15];
    float* out = (float*)d_out;

    k1<<<dim3(256), dim3(256), 0, stream>>>(x, psi_w, psi_b, theta_w, theta_b,
                                            phi_w, phi_b, h0_w, h1_w, h2_w, W_w);
    k2<<<dim3(512), dim3(256), 0, stream>>>();
    k3<<<dim3(256), dim3(512), 0, stream>>>();
    k4<<<dim3(512), dim3(512), 0, stream>>>(x, W_b, bn_g, bn_b, bn_m, bn_v, out);
}